// Round 3
// baseline (319.225 us; speedup 1.0000x reference)
//
#include <hip/hip_runtime.h>
#include <stdint.h>

// ---------------- constants ----------------
#define NCLS 20
#define STG_PER_WAVE 768
#define STG_TRIG 512
#define SURV_CAP 2048

__device__ __forceinline__ float sigm(float x) { return 1.0f / (1.0f + expf(-x)); }

// ---------------- K0: init ws ----------------
__global__ void k_init(unsigned int* hdr, unsigned int* hist) {
    int t = threadIdx.x;
    for (int i = t; i < 64; i += 1024) hdr[i] = 0u;
    for (int i = t; i < 3 * 4096; i += 1024) hist[i] = 0u;
}

// ---------------- K1/K2: streaming score pass ----------------
// hdr[0..2]  : main-pass append counts per level
// hdr[4..6]  : fallback append counts per level
// hdr[8..10] : Tsel bits per level
// hdr[12..14]: survivor counts per level
// Block = 1024 pixels x 1 anchor (obj + 20 cls channels), 256 thr x 4 px.
// L0: 100x3=300 blocks; L1: 25x3=75; L2: 7x3=21. Total 396.
template<int FB>
__global__ __launch_bounds__(256) void k_score(
    const float* __restrict__ obj0, const float* __restrict__ cls0,
    const float* __restrict__ obj1, const float* __restrict__ cls1,
    const float* __restrict__ obj2, const float* __restrict__ cls2,
    unsigned int* hdr, unsigned int* hist,
    unsigned long long* buf0, unsigned long long* buf1, unsigned long long* buf2,
    int cap0, int cap1, int cap2)
{
    int b = blockIdx.x;
    int L, tile, a, W;
    const float *obj, *cls; unsigned long long* gbuf; int cap;
    if (b < 300)      { L = 0; tile = b % 100;              a = b / 100; W = 320; obj = obj0; cls = cls0; gbuf = buf0; cap = cap0; }
    else if (b < 375) { int bb = b - 300; L = 1; tile = bb % 25; a = bb / 25; W = 160; obj = obj1; cls = cls1; gbuf = buf1; cap = cap1; }
    else              { int bb = b - 375; L = 2; tile = bb % 7;  a = bb / 7;  W = 80;  obj = obj2; cls = cls2; gbuf = buf2; cap = cap2; }
    const int P = W * W;
    if (FB) { if (hdr[L] >= 100u) return; }   // fallback not needed for this level

    __shared__ unsigned long long stage[4 * STG_PER_WAVE];
    __shared__ unsigned int lhist[4096];
    __shared__ int wcnt[4];

    const int t = threadIdx.x;
    const int wid = t >> 6, lane = t & 63;
    for (int i = t; i < 4096; i += 256) lhist[i] = 0u;
    if (lane == 0) wcnt[wid] = 0;
    __syncthreads();

    unsigned long long* wstage = stage + wid * STG_PER_WAVE;

    const int p0 = tile * 1024 + t * 4;      // 4 pixels/thread; P%4==0 for all levels
    const bool act = p0 < P;

    float so[4] = {0.f, 0.f, 0.f, 0.f};
    if (act) {
        float4 ov = *(const float4*)(obj + (size_t)a * P + p0);
        so[0] = sigm(ov.x); so[1] = sigm(ov.y); so[2] = sigm(ov.z); so[3] = sigm(ov.w);
    }
    #pragma unroll
    for (int c = 0; c < NCLS; c++) {
        if (act) {
            float4 cv = *(const float4*)(cls + (size_t)(a * NCLS + c) * P + p0);
            float sq[4];
            sq[0] = so[0] * sigm(cv.x); sq[1] = so[1] * sigm(cv.y);
            sq[2] = so[2] * sigm(cv.z); sq[3] = so[3] * sigm(cv.w);
            #pragma unroll
            for (int q = 0; q < 4; q++) {
                float s = sq[q];
                unsigned int bits = __float_as_uint(s);
                if (!FB && s >= 0.5f) {   // histogram only in main pass (no double count)
                    unsigned int bin = (bits - 0x3F000000u) >> 11;
                    if (bin > 4095u) bin = 4095u;
                    atomicAdd(&lhist[bin], 1u);
                }
                bool take = FB ? (s <= 0.7f) : (s > 0.7f);
                if (take) {
                    unsigned int ti = (unsigned int)(((p0 + q) * 3 + a) * NCLS + c);
                    unsigned long long key =
                        ((unsigned long long)bits << 32) | (unsigned long long)(0xFFFFFFFFu - ti);
                    int pos = atomicAdd(&wcnt[wid], 1);
                    if (pos < STG_PER_WAVE) wstage[pos] = key;
                }
            }
        }
        // wave-uniform flush check (no block barrier; wave LDS ops are in-order).
        // Max growth between checks = 256 (64 lanes x 4 px); trigger 512, cap 768.
        if (wcnt[wid] >= STG_TRIG) {
            int n = wcnt[wid]; if (n > STG_PER_WAVE) n = STG_PER_WAVE;
            unsigned int base = 0;
            if (lane == 0) {
                if (FB) base = hdr[L] + atomicAdd(&hdr[4 + L], (unsigned int)n);
                else    base = atomicAdd(&hdr[L], (unsigned int)n);
            }
            base = __shfl(base, 0);
            for (int i = lane; i < n; i += 64) {
                unsigned int gp = base + i;
                if (gp < (unsigned int)cap) gbuf[gp] = wstage[i];
            }
            if (lane == 0) wcnt[wid] = 0;
        }
    }
    // final wave flush
    {
        int n = wcnt[wid]; if (n > STG_PER_WAVE) n = STG_PER_WAVE;
        if (n > 0) {
            unsigned int base = 0;
            if (lane == 0) {
                if (FB) base = hdr[L] + atomicAdd(&hdr[4 + L], (unsigned int)n);
                else    base = atomicAdd(&hdr[L], (unsigned int)n);
            }
            base = __shfl(base, 0);
            for (int i = lane; i < n; i += 64) {
                unsigned int gp = base + i;
                if (gp < (unsigned int)cap) gbuf[gp] = wstage[i];
            }
        }
    }
    if (!FB) {
        __syncthreads();
        for (int i = t; i < 4096; i += 256) {
            unsigned int v = lhist[i];
            if (v) atomicAdd(&hist[L * 4096 + i], v);
        }
    }
}

// ---------------- K3: threshold select (3 waves, barrier-free) ----------------
__global__ void k_scan(unsigned int* hdr, const unsigned int* __restrict__ hist) {
    int t = threadIdx.x;
    int L = t >> 6, lane = t & 63;
    if (L >= 3) return;
    const unsigned int* h = hist + L * 4096;
    // lane owns descending-rank range [lane*64, lane*64+64)
    unsigned int s = 0;
    for (int k = 0; k < 64; k++) s += h[4095 - (lane * 64 + k)];
    unsigned int incl = s;
    #pragma unroll
    for (int off = 1; off < 64; off <<= 1) {
        unsigned int u = __shfl_up(incl, off);
        if (lane >= off) incl += u;
    }
    unsigned int excl = incl - s;
    if (excl < 100u && incl >= 100u) {
        unsigned int cum = excl;
        for (int k = 0; k < 64; k++) {
            cum += h[4095 - (lane * 64 + k)];
            if (cum >= 100u) {
                hdr[8 + L] = 0x3F000000u + ((unsigned int)(4095 - (lane * 64 + k)) << 11);
                break;
            }
        }
    }
    // if total < 100, Tsel stays 0 (select everything in buffer)
}

// ---------------- K4: compact survivors (>= Tsel) ----------------
__global__ void k_compact(unsigned int* hdr,
                          const unsigned long long* __restrict__ buf0,
                          const unsigned long long* __restrict__ buf1,
                          const unsigned long long* __restrict__ buf2,
                          int cap0, int cap1, int cap2,
                          unsigned long long* surv)
{
    int gt = blockIdx.x * blockDim.x + threadIdx.x;
    int gstep = gridDim.x * blockDim.x;
    int lane = threadIdx.x & 63;
    for (int L = 0; L < 3; L++) {
        const unsigned long long* buf = (L == 0) ? buf0 : (L == 1 ? buf1 : buf2);
        int cap = (L == 0) ? cap0 : (L == 1 ? cap1 : cap2);
        unsigned int cnt = hdr[L] + hdr[4 + L];
        int n = (int)((cnt < (unsigned int)cap) ? cnt : (unsigned int)cap);
        unsigned int ts = hdr[8 + L];
        for (int i = gt; i < n; i += gstep) {
            unsigned long long k = buf[i];
            bool takeIt = (unsigned int)(k >> 32) >= ts;
            unsigned long long m = __ballot(takeIt);
            if (takeIt) {
                int lead = __ffsll((long long)m) - 1;
                int pref = __popcll(m & ((1ull << lane) - 1ull));
                unsigned int base = 0;
                if (lane == lead) base = atomicAdd(&hdr[12 + L], (unsigned int)__popcll(m));
                base = __shfl(base, lead);
                unsigned int pos = base + (unsigned int)pref;
                if (pos < SURV_CAP) surv[L * SURV_CAP + pos] = k;
            }
        }
    }
}

// ---------------- K5: final select + decode + sort + NMS + output ----------------
__global__ __launch_bounds__(512) void k_final(
    const unsigned int* __restrict__ hdr,
    const unsigned long long* __restrict__ surv,
    const float* __restrict__ reg0, const float* __restrict__ reg1, const float* __restrict__ reg2,
    float* __restrict__ out)
{
    const int t = threadIdx.x;
    __shared__ unsigned long long svl[SURV_CAP];          // 16 KB staging
    __shared__ unsigned long long topk[300];
    __shared__ float bx[300][4];
    __shared__ float sc[300];
    __shared__ int   lb[300];
    __shared__ unsigned long long key2[300];
    __shared__ float sbx[300][4];
    __shared__ float ssc[300];
    __shared__ int   slb[300];
    __shared__ float sar[300];
    __shared__ unsigned long long supmat[300][5];
    __shared__ unsigned char keepA[300];

    for (int i = t; i < 300; i += 512) topk[i] = 0ull;
    __syncthreads();

    // per-level exact rank select (keys unique), survivors staged in LDS
    for (int L = 0; L < 3; L++) {
        int n = (int)hdr[12 + L]; if (n > SURV_CAP) n = SURV_CAP;
        const unsigned long long* sv = surv + L * SURV_CAP;
        for (int i = t; i < n; i += 512) svl[i] = sv[i];
        __syncthreads();
        for (int i = t; i < n; i += 512) {
            unsigned long long ki = svl[i];
            int r = 0;
            for (int j = 0; j < n; j++) r += (svl[j] > ki);
            if (r < 100) topk[L * 100 + r] = ki;
        }
        __syncthreads();
    }

    const int   Wl[3] = {320, 160, 80};
    const float Sl[3] = {8.f, 16.f, 32.f};
    const float AW[3][3] = {{12.f, 19.f, 40.f}, {36.f, 76.f, 72.f}, {142.f, 192.f, 459.f}};
    const float AH[3][3] = {{16.f, 36.f, 28.f}, {75.f, 55.f, 146.f}, {110.f, 243.f, 401.f}};

    for (int i = t; i < 300; i += 512) {
        unsigned long long k = topk[i];
        int L = i / 100;
        float s = __uint_as_float((unsigned int)(k >> 32));
        unsigned int ti = 0xFFFFFFFFu - (unsigned int)k;
        float x1 = 0.f, y1 = 0.f, x2 = 0.f, y2 = 0.f; int c = 0;
        if (k != 0ull) {
            c = (int)(ti % NCLS);
            unsigned int na = ti / NCLS;
            int a = (int)(na % 3);
            int p = (int)(na / 3);
            int W = Wl[L]; int P = W * W;
            int px = p % W, py = p / W;
            const float* reg = (L == 0) ? reg0 : (L == 1 ? reg1 : reg2);
            float tx = reg[(a * 4 + 0) * P + p];
            float ty = reg[(a * 4 + 1) * P + p];
            float tw = reg[(a * 4 + 2) * P + p];
            float th = reg[(a * 4 + 3) * P + p];
            float st = Sl[L];
            float cx = (sigm(tx) * 3.0f - 1.5f + ((float)px + 0.5f)) * st;
            float cy = (sigm(ty) * 3.0f - 1.5f + ((float)py + 0.5f)) * st;
            float w = expf(tw) * AW[L][a];
            float h = expf(th) * AH[L][a];
            x1 = cx - 0.5f * w; y1 = cy - 0.5f * h; x2 = cx + 0.5f * w; y2 = cy + 0.5f * h;
        } else {
            s = 0.f;
        }
        bx[i][0] = x1; bx[i][1] = y1; bx[i][2] = x2; bx[i][3] = y2;
        sc[i] = s; lb[i] = c;
        // stable argsort(-scores): score desc, concat-position asc
        key2[i] = (k & 0xFFFFFFFF00000000ull) | (unsigned long long)(299 - i);
    }
    __syncthreads();

    for (int i = t; i < 300; i += 512) {
        unsigned long long ki = key2[i];
        int r = 0;
        for (int j = 0; j < 300; j++) r += (key2[j] > ki);
        sbx[r][0] = bx[i][0]; sbx[r][1] = bx[i][1]; sbx[r][2] = bx[i][2]; sbx[r][3] = bx[i][3];
        ssc[r] = sc[i]; slb[r] = lb[i];
    }
    __syncthreads();
    for (int i = t; i < 300; i += 512)
        sar[i] = (sbx[i][2] - sbx[i][0]) * (sbx[i][3] - sbx[i][1]);
    __syncthreads();

    // suppression matrix rows as bitmasks
    for (int i = t; i < 300; i += 512) {
        float ax1 = sbx[i][0], ay1 = sbx[i][1], ax2 = sbx[i][2], ay2 = sbx[i][3], aa = sar[i];
        int al = slb[i];
        unsigned long long wds[5] = {0ull, 0ull, 0ull, 0ull, 0ull};
        for (int j = 0; j < 300; j++) {
            float xx1 = fmaxf(ax1, sbx[j][0]);
            float yy1 = fmaxf(ay1, sbx[j][1]);
            float xx2 = fminf(ax2, sbx[j][2]);
            float yy2 = fminf(ay2, sbx[j][3]);
            float iw = fmaxf(1e-10f, xx2 - xx1);
            float ih = fmaxf(1e-10f, yy2 - yy1);
            float inter = iw * ih;
            float iou = inter / (aa + sar[j] - inter);
            if (iou > 0.5f && al == slb[j]) wds[j >> 6] |= (1ull << (j & 63));
        }
        #pragma unroll
        for (int w = 0; w < 5; w++) supmat[i][w] = wds[w];
    }
    __syncthreads();

    // greedy NMS: wave 0, all state in named registers (no runtime-indexed arrays)
    if (t < 64) {
        const int l = t;
        unsigned long long v0 = __ballot(ssc[l]       > 0.01f);
        unsigned long long v1 = __ballot(ssc[64 + l]  > 0.01f);
        unsigned long long v2 = __ballot(ssc[128 + l] > 0.01f);
        unsigned long long v3 = __ballot(ssc[192 + l] > 0.01f);
        unsigned long long v4 = __ballot((256 + l) < 300 ? (ssc[256 + l] > 0.01f) : false);

        unsigned long long s0 = 0, s1 = 0, s2 = 0, s3 = 0, s4 = 0;
        unsigned long long k0 = 0, k1 = 0, k2 = 0, k3 = 0, k4 = 0;
        unsigned long long rA0 = supmat[0][0], rA1 = supmat[0][1], rA2 = supmat[0][2],
                           rA3 = supmat[0][3], rA4 = supmat[0][4];
        for (int i = 0; i < 300; i++) {
            // prefetch next row (independent of this iteration's decision)
            unsigned long long rB0 = 0, rB1 = 0, rB2 = 0, rB3 = 0, rB4 = 0;
            if (i + 1 < 300) {
                rB0 = supmat[i + 1][0]; rB1 = supmat[i + 1][1]; rB2 = supmat[i + 1][2];
                rB3 = supmat[i + 1][3]; rB4 = supmat[i + 1][4];
            }
            int w = i >> 6, b = i & 63;
            unsigned long long sw = (w == 0) ? s0 : (w == 1) ? s1 : (w == 2) ? s2 : (w == 3) ? s3 : s4;
            unsigned long long vw = (w == 0) ? v0 : (w == 1) ? v1 : (w == 2) ? v2 : (w == 3) ? v3 : v4;
            bool kept = (((sw >> b) & 1ull) == 0ull) && (((vw >> b) & 1ull) != 0ull);
            unsigned long long kb = kept ? (1ull << b) : 0ull;
            k0 |= (w == 0) ? kb : 0ull; k1 |= (w == 1) ? kb : 0ull; k2 |= (w == 2) ? kb : 0ull;
            k3 |= (w == 3) ? kb : 0ull; k4 |= (w == 4) ? kb : 0ull;
            unsigned long long tail = (b == 63) ? 0ull : ((~0ull) << (b + 1));
            unsigned long long e = kept ? ~0ull : 0ull;
            s0 |= rA0 & e & ((w == 0) ? tail : 0ull);
            s1 |= rA1 & e & ((w == 1) ? tail : ((w < 1) ? ~0ull : 0ull));
            s2 |= rA2 & e & ((w == 2) ? tail : ((w < 2) ? ~0ull : 0ull));
            s3 |= rA3 & e & ((w == 3) ? tail : ((w < 3) ? ~0ull : 0ull));
            s4 |= rA4 & e & ((w == 4) ? tail : ((w < 4) ? ~0ull : 0ull));
            rA0 = rB0; rA1 = rB1; rA2 = rB2; rA3 = rB3; rA4 = rB4;
        }
        keepA[l]       = (unsigned char)((k0 >> l) & 1ull);
        keepA[64 + l]  = (unsigned char)((k1 >> l) & 1ull);
        keepA[128 + l] = (unsigned char)((k2 >> l) & 1ull);
        keepA[192 + l] = (unsigned char)((k3 >> l) & 1ull);
        if (256 + l < 300) keepA[256 + l] = (unsigned char)((k4 >> l) & 1ull);
    }
    __syncthreads();

    for (int i = t; i < 300; i += 512) {
        out[i * 4 + 0] = sbx[i][0];
        out[i * 4 + 1] = sbx[i][1];
        out[i * 4 + 2] = sbx[i][2];
        out[i * 4 + 3] = sbx[i][3];
        float kp = keepA[i] ? 1.f : 0.f;
        out[1200 + i] = ssc[i] * kp;
        out[1500 + i] = (float)slb[i];
        out[1800 + i] = kp;
    }
}

// ---------------- launch ----------------
extern "C" void kernel_launch(void* const* d_in, const int* in_sizes, int n_in,
                              void* d_out, int out_size, void* d_ws, size_t ws_size,
                              hipStream_t stream)
{
    const float* obj0 = (const float*)d_in[0];
    const float* cls0 = (const float*)d_in[1];
    const float* reg0 = (const float*)d_in[2];
    const float* obj1 = (const float*)d_in[3];
    const float* cls1 = (const float*)d_in[4];
    const float* reg1 = (const float*)d_in[5];
    const float* obj2 = (const float*)d_in[6];
    const float* cls2 = (const float*)d_in[7];
    const float* reg2 = (const float*)d_in[8];

    char* ws = (char*)d_ws;
    unsigned int* hdr  = (unsigned int*)ws;                       // 256 B
    unsigned int* hist = (unsigned int*)(ws + 256);               // 48 KB
    unsigned long long* surv = (unsigned long long*)(ws + 256 + 49152); // 48 KB
    const size_t off = 131072;

    size_t avail = (ws_size > off) ? (ws_size - off) : 0;
    long long ents = (long long)(avail / 8);
    long long cap0 = ents * 16 / 21; if (cap0 > 6144000LL) cap0 = 6144000LL;
    long long cap1 = ents * 4 / 21;  if (cap1 > 1536000LL) cap1 = 1536000LL;
    long long cap2 = ents * 1 / 21;  if (cap2 > 384000LL)  cap2 = 384000LL;
    if (cap0 < 1) cap0 = 1; if (cap1 < 1) cap1 = 1; if (cap2 < 1) cap2 = 1;

    unsigned long long* buf0 = (unsigned long long*)(ws + off);
    unsigned long long* buf1 = buf0 + cap0;
    unsigned long long* buf2 = buf1 + cap1;

    k_init<<<1, 1024, 0, stream>>>(hdr, hist);
    k_score<0><<<396, 256, 0, stream>>>(obj0, cls0, obj1, cls1, obj2, cls2,
                                        hdr, hist, buf0, buf1, buf2,
                                        (int)cap0, (int)cap1, (int)cap2);
    k_score<1><<<396, 256, 0, stream>>>(obj0, cls0, obj1, cls1, obj2, cls2,
                                        hdr, hist, buf0, buf1, buf2,
                                        (int)cap0, (int)cap1, (int)cap2);
    k_scan<<<1, 192, 0, stream>>>(hdr, hist);
    k_compact<<<128, 256, 0, stream>>>(hdr, buf0, buf1, buf2,
                                       (int)cap0, (int)cap1, (int)cap2, surv);
    k_final<<<1, 512, 0, stream>>>(hdr, surv, reg0, reg1, reg2, (float*)d_out);
}